// Round 1
// baseline (34037.894 us; speedup 1.0000x reference)
//
#include <hip/hip_runtime.h>
#include <hip/hip_bf16.h>

// NeuralODE: B=256, Z=1024, H=2048, T=128, explicit Euler, 127 steps.
// Round 0: sync-free baseline. 16 workgroups x 512 threads; each wg owns 16
// batch rows and runs all 127 steps locally (no inter-wg communication).
// bf16 MFMA 16x16x32, fp32 state kept in the output trajectory itself.

#define ZD 1024
#define HD 2048
#define TT 128
#define ZT (ZD * TT)  // 131072 elements per batch row in out[B][Z][T]

typedef __attribute__((ext_vector_type(8))) short bfrag;  // 8 bf16 (4 VGPRs)
typedef __attribute__((ext_vector_type(4))) float ffrag;  // 4 fp32 acc

__device__ __forceinline__ short f2bf(float f) {
  union { float f; unsigned u; } x; x.f = f;
  unsigned r = x.u + 0x7fffu + ((x.u >> 16) & 1u);  // RNE
  return (short)(r >> 16);
}

// XOR-swizzle of 8-element (16 B) blocks inside a 1024-wide bf16 LDS row.
// Breaks the stride-2048B 16-way bank conflict on A-fragment reads -> 2-way.
__device__ __forceinline__ int swz(int row, int k) {
  return row * 1024 + ((((k >> 3) ^ row) << 3) | (k & 7));
}

template <int USEB>
__global__ __launch_bounds__(512, 2) void ode_kernel(
    const float* __restrict__ z0, const float* __restrict__ ts,
    const float* __restrict__ W1f, const float* __restrict__ wt,
    const float* __restrict__ b1, const float* __restrict__ W2f,
    const float* __restrict__ b2,
    const short* __restrict__ W1b, const short* __restrict__ W2b,
    float* __restrict__ out) {
  // 16 rows of z as bf16 (A-operand mirror), one 1024-col half of h as bf16.
  __shared__ short zb[16 * 1024];  // 32 KB
  __shared__ short hb[16 * 1024];  // 32 KB  (total 64 KB = static LDS limit)

  const int tid = threadIdx.x;
  const int wv = tid >> 6;         // wave 0..7
  const int lane = tid & 63;
  const int l16 = lane & 15;
  const int quad = lane >> 4;
  const int r0 = blockIdx.x << 4;  // first batch row of this wg

  // ---- init: load z0 rows, write traj[:, :, 0], fill bf16 z mirror ----
  for (int i = tid; i < (16 * ZD) / 4; i += 512) {
    const int c4 = i << 2;
    const int r = c4 >> 10, c = c4 & (ZD - 1);
    const float4 v = *(const float4*)(z0 + (size_t)(r0 + r) * ZD + c);
    float vv[4] = {v.x, v.y, v.z, v.w};
    float* op = out + (size_t)(r0 + r) * ZT;
#pragma unroll
    for (int j = 0; j < 4; ++j) {
      op[(size_t)(c + j) * TT] = vv[j];
      zb[swz(r, c + j)] = f2bf(vv[j]);
    }
  }
  __syncthreads();

  for (int t = 0; t < TT - 1; ++t) {
    const float tv = ts[t];
    const float dtv = ts[t + 1] - tv;
    ffrag accB[8];
#pragma unroll
    for (int i = 0; i < 8; ++i) accB[i] = ffrag{0.f, 0.f, 0.f, 0.f};

#pragma unroll 1
    for (int half = 0; half < 2; ++half) {
      // ---- Phase A: h[:, half*1024 : (half+1)*1024] ----
      ffrag accA[8];
#pragma unroll
      for (int i = 0; i < 8; ++i) accA[i] = ffrag{0.f, 0.f, 0.f, 0.f};
      const int hbase = half * 1024 + wv * 128;  // this wave's 128 h-cols

      for (int kk = 0; kk < 32; ++kk) {          // K = z-dim = 1024
        const int k0 = (kk << 5) + (quad << 3);
        const bfrag a = *(const bfrag*)(zb + swz(l16, k0));
        bfrag bm[8];
        if (USEB) {
#pragma unroll
          for (int tn = 0; tn < 8; ++tn)
            bm[tn] = *(const bfrag*)(W1b + (size_t)(hbase + tn * 16 + l16) * ZD + k0);
        } else {
#pragma unroll
          for (int tn = 0; tn < 8; ++tn) {
            const float* p = W1f + (size_t)(hbase + tn * 16 + l16) * ZD + k0;
            const float4 u = *(const float4*)p;
            const float4 w = *(const float4*)(p + 4);
            bfrag bb;
            bb[0] = f2bf(u.x); bb[1] = f2bf(u.y); bb[2] = f2bf(u.z); bb[3] = f2bf(u.w);
            bb[4] = f2bf(w.x); bb[5] = f2bf(w.y); bb[6] = f2bf(w.z); bb[7] = f2bf(w.w);
            bm[tn] = bb;
          }
        }
#pragma unroll
        for (int tn = 0; tn < 8; ++tn)
          accA[tn] = __builtin_amdgcn_mfma_f32_16x16x32_bf16(a, bm[tn], accA[tn], 0, 0, 0);
      }
      // epilogue A: tanh(acc + t*wt + b1) -> LDS h (bf16, swizzled)
#pragma unroll
      for (int tn = 0; tn < 8; ++tn) {
        const int hc = hbase + tn * 16 + l16;
        const float wtv = wt[hc], b1v = b1[hc];
        const int colL = hc - half * 1024;
#pragma unroll
        for (int rg = 0; rg < 4; ++rg) {
          const int row = (quad << 2) + rg;
          const float hv = tanhf(accA[tn][rg] + tv * wtv + b1v);
          hb[swz(row, colL)] = f2bf(hv);
        }
      }
      __syncthreads();  // h half ready

      // ---- Phase B partial: accumulate dz over this h half ----
      const int koff = half * 1024;
      for (int kk = 0; kk < 32; ++kk) {
        const int kl = (kk << 5) + (quad << 3);
        const bfrag a = *(const bfrag*)(hb + swz(l16, kl));
        bfrag bm[8];
        if (USEB) {
#pragma unroll
          for (int tn = 0; tn < 8; ++tn)
            bm[tn] = *(const bfrag*)(W2b + (size_t)(wv * 128 + tn * 16 + l16) * HD + koff + kl);
        } else {
#pragma unroll
          for (int tn = 0; tn < 8; ++tn) {
            const float* p = W2f + (size_t)(wv * 128 + tn * 16 + l16) * HD + koff + kl;
            const float4 u = *(const float4*)p;
            const float4 w = *(const float4*)(p + 4);
            bfrag bb;
            bb[0] = f2bf(u.x); bb[1] = f2bf(u.y); bb[2] = f2bf(u.z); bb[3] = f2bf(u.w);
            bb[4] = f2bf(w.x); bb[5] = f2bf(w.y); bb[6] = f2bf(w.z); bb[7] = f2bf(w.w);
            bm[tn] = bb;
          }
        }
#pragma unroll
        for (int tn = 0; tn < 8; ++tn)
          accB[tn] = __builtin_amdgcn_mfma_f32_16x16x32_bf16(a, bm[tn], accB[tn], 0, 0, 0);
      }
      __syncthreads();  // h half consumed; safe to overwrite next half
    }

    // ---- epilogue B: z' = z + dt*(dz + b2); fp32 state lives in `out` ----
#pragma unroll
    for (int tn = 0; tn < 8; ++tn) {
      const int n = wv * 128 + tn * 16 + l16;  // z column
      const float b2v = b2[n];
#pragma unroll
      for (int rg = 0; rg < 4; ++rg) {
        const int row = (quad << 2) + rg;
        float* zp = out + (size_t)(r0 + row) * ZT + (size_t)n * TT + t;
        const float znew = zp[0] + dtv * (accB[tn][rg] + b2v);
        zp[1] = znew;
        zb[swz(row, n)] = f2bf(znew);
      }
    }
    __syncthreads();  // zb stable before next step's Phase A
  }
}

__global__ void cvt_kernel(const float* __restrict__ src, short* __restrict__ dst, int n) {
  const int i = (blockIdx.x * 256 + threadIdx.x) << 2;
  if (i >= n) return;
  const float4 v = *(const float4*)(src + i);
  short4 o;
  o.x = f2bf(v.x); o.y = f2bf(v.y); o.z = f2bf(v.z); o.w = f2bf(v.w);
  *(short4*)(dst + i) = o;
}

extern "C" void kernel_launch(void* const* d_in, const int* in_sizes, int n_in,
                              void* d_out, int out_size, void* d_ws, size_t ws_size,
                              hipStream_t stream) {
  const float* z0 = (const float*)d_in[0];
  const float* ts = (const float*)d_in[1];
  const float* W1 = (const float*)d_in[2];
  const float* wt = (const float*)d_in[3];
  const float* b1 = (const float*)d_in[4];
  const float* W2 = (const float*)d_in[5];
  const float* b2 = (const float*)d_in[6];
  float* out = (float*)d_out;

  const int wn = HD * ZD;  // 2M elements per weight matrix
  const size_t need = (size_t)wn * 2 * sizeof(short);  // 8 MB
  if (ws_size >= need) {
    short* wsb = (short*)d_ws;
    cvt_kernel<<<wn / 1024, 256, 0, stream>>>(W1, wsb, wn);
    cvt_kernel<<<wn / 1024, 256, 0, stream>>>(W2, wsb + wn, wn);
    ode_kernel<1><<<16, 512, 0, stream>>>(z0, ts, W1, wt, b1, W2, b2,
                                          wsb, wsb + wn, out);
  } else {
    ode_kernel<0><<<16, 512, 0, stream>>>(z0, ts, W1, wt, b1, W2, b2,
                                          nullptr, nullptr, out);
  }
}

// Round 2
// 6845.683 us; speedup vs baseline: 4.9722x; 4.9722x over previous
//
#include <hip/hip_runtime.h>
#include <hip/hip_bf16.h>

// NeuralODE: B=256, Z=1024, H=2048, T=128, explicit Euler, 127 steps.
// Round 1: 256 WGs (one per CU). WG b -> (mg = b>>4, ng = 2*(b&7)+((b>>3)&1)).
//   GEMM1: h[mg*16..+16][ng*128..+128], GEMM2: z[mg*16..+16][ng*64..+64].
// Producers and consumers of row-group mg are the same 16 WGs -> sync via
// per-row-group monotonic counters (device-scope release/acquire), no grid
// barrier. ng-swizzle co-locates weight-slice sharers on one XCD (L2 reuse).
// All state in __device__ statics; no ws_size dependence.

#define ZD 1024
#define HD 2048
#define TT 128
#define BB 256
#define ZT (ZD * TT)

typedef __attribute__((ext_vector_type(8))) short bfrag;  // 8 bf16
typedef __attribute__((ext_vector_type(4))) float ffrag;  // 4 fp32

__device__ short g_W1b[HD * ZD];   // 4 MB bf16, [h][z]
__device__ short g_W2b[ZD * HD];   // 4 MB bf16, [z][h]
__device__ short g_zb[BB * ZD];    // bf16 z mirror
__device__ short g_hb[BB * HD];    // bf16 hidden
__device__ float g_zf[BB * ZD];    // fp32 z state
__device__ unsigned g_cnt[64];     // [mg]=z gen counter, [16+mg]=h gen counter

__device__ __forceinline__ short f2bf(float f) {
  union { float f; unsigned u; } x; x.f = f;
  unsigned r = x.u + 0x7fffu + ((x.u >> 16) & 1u);  // RNE
  return (short)(r >> 16);
}

// XOR-swizzle of 16B blocks within an LDS row (kills stride bank conflicts).
__device__ __forceinline__ int swzA(int row, int k) {  // 1024-wide rows
  return (row << 10) + ((((k >> 3) ^ row) << 3) | (k & 7));
}
__device__ __forceinline__ int swzH(int row, int k) {  // 2048-wide rows
  return (row << 11) + ((((k >> 3) ^ row) << 3) | (k & 7));
}

__global__ void zero_cnt_kernel() {
  if (threadIdx.x < 64) g_cnt[threadIdx.x] = 0u;
}

__global__ void cvt_weights_kernel(const float* __restrict__ W1,
                                   const float* __restrict__ W2) {
  const int i = (blockIdx.x * 256 + threadIdx.x) << 2;  // grid covers 2M elems
  {
    const float4 v = *(const float4*)(W1 + i);
    short4 o; o.x = f2bf(v.x); o.y = f2bf(v.y); o.z = f2bf(v.z); o.w = f2bf(v.w);
    *(short4*)(g_W1b + i) = o;
  }
  {
    const float4 v = *(const float4*)(W2 + i);
    short4 o; o.x = f2bf(v.x); o.y = f2bf(v.y); o.z = f2bf(v.z); o.w = f2bf(v.w);
    *(short4*)(g_W2b + i) = o;
  }
}

__global__ __launch_bounds__(512, 2) void ode_main(
    const float* __restrict__ z0, const float* __restrict__ ts,
    const float* __restrict__ wt, const float* __restrict__ b1,
    const float* __restrict__ b2, float* __restrict__ out) {
  __shared__ short buf[32 * 1024];  // 64 KB: z-stage (32K) / h-stage (64K) / red

  const int tid = threadIdx.x;
  const int wv = tid >> 6, lane = tid & 63, l16 = lane & 15, quad = lane >> 4;
  const int b = blockIdx.x;
  const int ng = ((b & 7) << 1) | ((b >> 3) & 1);  // same-ng -> same XCD
  const int mg = b >> 4;
  const int r0 = mg << 4;

  // ---- init: z slice rows [r0,+16) cols [ng*64,+64); traj t=0 ----
  {
    const int c0 = ng << 6;
    for (int i = tid; i < 16 * 64; i += 512) {
      const int r = i >> 6, c = c0 + (i & 63);
      const float v = z0[(r0 + r) * ZD + c];
      g_zf[(r0 + r) * ZD + c] = v;
      g_zb[(r0 + r) * ZD + c] = f2bf(v);
      out[(size_t)(r0 + r) * ZT + (size_t)c * TT] = v;
    }
    __syncthreads();
    if (tid == 0)
      __hip_atomic_fetch_add(&g_cnt[mg], 1u, __ATOMIC_RELEASE,
                             __HIP_MEMORY_SCOPE_AGENT);
  }

  for (int t = 0; t < TT - 1; ++t) {
    const float tv = ts[t];
    const float dtv = ts[t + 1] - tv;

    // ---- wait: z generation t complete for rows mg ----
    if (tid == 0) {
      const unsigned tgt = 16u * (unsigned)(t + 1);
      while (__hip_atomic_load(&g_cnt[mg], __ATOMIC_ACQUIRE,
                               __HIP_MEMORY_SCOPE_AGENT) < tgt)
        __builtin_amdgcn_s_sleep(2);
    }
    __syncthreads();

    // ---- stage z rows (16x1024 bf16 = 32 KB) into LDS, swizzled ----
#pragma unroll
    for (int i = 0; i < 4; ++i) {
      const int e = (tid + i * 512) << 3;
      const int r = e >> 10, k = e & (ZD - 1);
      const bfrag v = *(const bfrag*)(g_zb + (r0 + r) * ZD + k);
      *(bfrag*)(buf + swzA(r, k)) = v;
    }
    __syncthreads();

    // ---- GEMM1: wave computes h rows [r0,+16) cols [hc0,+16), K=1024 ----
    const int hc0 = (ng << 7) + (wv << 4);
    ffrag accA = {0.f, 0.f, 0.f, 0.f};
#pragma unroll 4
    for (int kk = 0; kk < 32; ++kk) {
      const int k0 = (kk << 5) + (quad << 3);
      const bfrag a = *(const bfrag*)(buf + swzA(l16, k0));
      const bfrag bm = *(const bfrag*)(g_W1b + (size_t)(hc0 + l16) * ZD + k0);
      accA = __builtin_amdgcn_mfma_f32_16x16x32_bf16(a, bm, accA, 0, 0, 0);
    }
    {
      const int hc = hc0 + l16;
      const float wtv = wt[hc], b1v = b1[hc];
#pragma unroll
      for (int rg = 0; rg < 4; ++rg) {
        const int row = (quad << 2) + rg;
        g_hb[(r0 + row) * HD + hc] = f2bf(tanhf(accA[rg] + tv * wtv + b1v));
      }
    }
    __syncthreads();  // whole WG's h slice written
    if (tid == 0)
      __hip_atomic_fetch_add(&g_cnt[16 + mg], 1u, __ATOMIC_RELEASE,
                             __HIP_MEMORY_SCOPE_AGENT);

    // ---- wait: h generation t complete for rows mg ----
    if (tid == 0) {
      const unsigned tgt = 16u * (unsigned)(t + 1);
      while (__hip_atomic_load(&g_cnt[16 + mg], __ATOMIC_ACQUIRE,
                               __HIP_MEMORY_SCOPE_AGENT) < tgt)
        __builtin_amdgcn_s_sleep(2);
    }
    __syncthreads();

    // ---- stage h rows (16x2048 bf16 = 64 KB) into LDS, swizzled ----
#pragma unroll
    for (int i = 0; i < 8; ++i) {
      const int e = (tid + i * 512) << 3;
      const int r = e >> 11, k = e & (HD - 1);
      const bfrag v = *(const bfrag*)(g_hb + (r0 + r) * HD + k);
      *(bfrag*)(buf + swzH(r, k)) = v;
    }
    __syncthreads();

    // ---- GEMM2 (2-way K-split): wave = kh*4+nq; cols [zc0,+16), K half ----
    const int nq = wv & 3, kh = wv >> 2;
    const int zc0 = (ng << 6) + (nq << 4);
    ffrag accB = {0.f, 0.f, 0.f, 0.f};
#pragma unroll 4
    for (int kk = 0; kk < 32; ++kk) {
      const int k0 = (kh << 10) + (kk << 5) + (quad << 3);
      const bfrag a = *(const bfrag*)(buf + swzH(l16, k0));
      const bfrag bm = *(const bfrag*)(g_W2b + (size_t)(zc0 + l16) * HD + k0);
      accB = __builtin_amdgcn_mfma_f32_16x16x32_bf16(a, bm, accB, 0, 0, 0);
    }
    __syncthreads();  // h-stage reads done; buf reusable for reduction
    float* red = (float*)buf;
    if (kh == 1) *(ffrag*)(red + (((nq << 6) + lane) << 2)) = accB;
    __syncthreads();
    if (kh == 0) {
      const ffrag o = *(const ffrag*)(red + (((nq << 6) + lane) << 2));
      accB += o;
      const int zc = zc0 + l16;
      const float b2v = b2[zc];
#pragma unroll
      for (int rg = 0; rg < 4; ++rg) {
        const int row = (quad << 2) + rg;
        const int gi = (r0 + row) * ZD + zc;
        const float zn = g_zf[gi] + dtv * (accB[rg] + b2v);
        g_zf[gi] = zn;
        g_zb[gi] = f2bf(zn);
        out[(size_t)(r0 + row) * ZT + (size_t)zc * TT + (t + 1)] = zn;
      }
    }
    __syncthreads();  // all z-slice writes done
    if (tid == 0)
      __hip_atomic_fetch_add(&g_cnt[mg], 1u, __ATOMIC_RELEASE,
                             __HIP_MEMORY_SCOPE_AGENT);
  }
}

extern "C" void kernel_launch(void* const* d_in, const int* in_sizes, int n_in,
                              void* d_out, int out_size, void* d_ws, size_t ws_size,
                              hipStream_t stream) {
  const float* z0 = (const float*)d_in[0];
  const float* ts = (const float*)d_in[1];
  const float* W1 = (const float*)d_in[2];
  const float* wt = (const float*)d_in[3];
  const float* b1 = (const float*)d_in[4];
  const float* W2 = (const float*)d_in[5];
  const float* b2 = (const float*)d_in[6];
  float* out = (float*)d_out;

  zero_cnt_kernel<<<1, 64, 0, stream>>>();
  cvt_weights_kernel<<<(HD * ZD) / 1024, 256, 0, stream>>>(W1, W2);
  ode_main<<<256, 512, 0, stream>>>(z0, ts, wt, b1, b2, out);
}